// Round 1
// baseline (830.959 us; speedup 1.0000x reference)
//
#include <hip/hip_runtime.h>

#define N_NODES 100000
#define N_EDGES 1600000
#define HIDDEN 64

// K1: edge type + per-(dst,rel) counts
__global__ void k_edge_type(const int* __restrict__ ei, const int* __restrict__ ntype,
                            unsigned char* __restrict__ et, int* __restrict__ cnt) {
    int e = blockIdx.x * blockDim.x + threadIdx.x;
    if (e >= N_EDGES) return;
    int s = ei[e], d = ei[N_EDGES + e];
    int t = (ntype[s] == ntype[d]) ? 1 : 0;
    et[e] = (unsigned char)t;
    atomicAdd(&cnt[d * 2 + t], 1);
}

// K2: layer-1 edge aggregation: one wave (64 lanes) per edge.
// agg[dst][rel][c] += h0[src][c] * norm   where h0[n] = emb[x[n]]
__global__ void k_aggregate1(const int* __restrict__ ei, const unsigned char* __restrict__ et,
                             const int* __restrict__ cnt, const int* __restrict__ x,
                             const float* __restrict__ emb, float* __restrict__ agg) {
    long long gid = (long long)blockIdx.x * blockDim.x + threadIdx.x;
    int e = (int)(gid >> 6);
    int lane = (int)(gid & 63);
    if (e >= N_EDGES) return;
    int s = ei[e], d = ei[N_EDGES + e];
    int t = et[e];
    int c = cnt[d * 2 + t];
    float norm = 1.0f / (float)(c > 1 ? c : 1);
    float v = emb[(long long)x[s] * HIDDEN + lane] * norm;
    atomicAdd(&agg[((long long)d * 2 + t) * HIDDEN + lane], v);
}

// K3: layer-1 dense transform + relu. One wave per node, lane = output channel.
// h1[n][o] = relu( agg[n][0][:]@W1[0][:,o] + agg[n][1][:]@W1[1][:,o] + h0[n][:]@root1[:,o] + b1[o] )
__global__ void k_layer1(const int* __restrict__ x, const float* __restrict__ emb,
                         const float* __restrict__ agg,
                         const float* __restrict__ W1, const float* __restrict__ root1,
                         const float* __restrict__ b1, float* __restrict__ h1) {
    int gid = blockIdx.x * blockDim.x + threadIdx.x;
    int n = gid >> 6;
    int o = gid & 63;
    if (n >= N_NODES) return;
    const float* a0 = &agg[(long long)n * 128];
    const float* a1 = a0 + 64;
    const float* hv = &emb[(long long)x[n] * 64];
    float acc = b1[o];
#pragma unroll 8
    for (int h = 0; h < 64; ++h) {
        acc += a0[h] * W1[h * 64 + o];            // W1[0][h][o]
        acc += a1[h] * W1[4096 + h * 64 + o];     // W1[1][h][o]
        acc += hv[h] * root1[h * 64 + o];
    }
    h1[gid] = acc > 0.f ? acc : 0.f;
}

// K4: layer-2 per-node scalars: s_r[n] = h1[n]·W2[r], out[n] = h1[n]·root2 + b2
__global__ void k_layer2_node(const float* __restrict__ h1, const float* __restrict__ W2,
                              const float* __restrict__ root2, const float* __restrict__ b2,
                              float* __restrict__ s, float* __restrict__ out) {
    int gid = blockIdx.x * blockDim.x + threadIdx.x;
    int n = gid >> 6;
    int c = gid & 63;
    if (n >= N_NODES) return;
    float v = h1[gid];
    float d0 = v * W2[c];          // W2[0][c][0]
    float d1 = v * W2[64 + c];     // W2[1][c][0]
    float d2 = v * root2[c];
    for (int off = 32; off >= 1; off >>= 1) {
        d0 += __shfl_down(d0, off);
        d1 += __shfl_down(d1, off);
        d2 += __shfl_down(d2, off);
    }
    if (c == 0) {
        s[n] = d0;
        s[N_NODES + n] = d1;
        out[n] = d2 + b2[0];
    }
}

// K5: layer-2 edge aggregation, scalar per edge.
__global__ void k_aggregate2(const int* __restrict__ ei, const unsigned char* __restrict__ et,
                             const int* __restrict__ cnt, const float* __restrict__ s,
                             float* __restrict__ out) {
    int e = blockIdx.x * blockDim.x + threadIdx.x;
    if (e >= N_EDGES) return;
    int sn = ei[e], d = ei[N_EDGES + e];
    int t = et[e];
    int c = cnt[d * 2 + t];
    float norm = 1.0f / (float)(c > 1 ? c : 1);
    atomicAdd(&out[d], s[t * N_NODES + sn] * norm);
}

extern "C" void kernel_launch(void* const* d_in, const int* in_sizes, int n_in,
                              void* d_out, int out_size, void* d_ws, size_t ws_size,
                              hipStream_t stream) {
    const int* x      = (const int*)d_in[0];
    const int* ei     = (const int*)d_in[1];
    const int* ntype  = (const int*)d_in[2];
    const float* emb  = (const float*)d_in[3];
    const float* W1   = (const float*)d_in[4];
    const float* root1= (const float*)d_in[5];
    const float* b1   = (const float*)d_in[6];
    const float* W2   = (const float*)d_in[7];
    const float* root2= (const float*)d_in[8];
    const float* b2   = (const float*)d_in[9];
    float* out = (float*)d_out;

    char* ws = (char*)d_ws;
    size_t off = 0;
    auto alloc = [&](size_t bytes) -> void* {
        void* p = ws + off;
        off = (off + bytes + 255) & ~(size_t)255;
        return p;
    };
    int*   cnt = (int*)  alloc((size_t)N_NODES * 2 * sizeof(int));
    unsigned char* et = (unsigned char*)alloc((size_t)N_EDGES);
    float* agg = (float*)alloc((size_t)N_NODES * 2 * HIDDEN * sizeof(float));
    float* h1  = (float*)alloc((size_t)N_NODES * HIDDEN * sizeof(float));
    float* s   = (float*)alloc((size_t)N_NODES * 2 * sizeof(float));

    hipMemsetAsync(cnt, 0, (size_t)N_NODES * 2 * sizeof(int), stream);
    hipMemsetAsync(agg, 0, (size_t)N_NODES * 2 * HIDDEN * sizeof(float), stream);

    k_edge_type<<<(N_EDGES + 255) / 256, 256, 0, stream>>>(ei, ntype, et, cnt);

    long long thr1 = (long long)N_EDGES * 64;
    k_aggregate1<<<(unsigned)((thr1 + 255) / 256), 256, 0, stream>>>(ei, et, cnt, x, emb, agg);

    k_layer1<<<(N_NODES * 64 + 255) / 256, 256, 0, stream>>>(x, emb, agg, W1, root1, b1, h1);

    k_layer2_node<<<(N_NODES * 64 + 255) / 256, 256, 0, stream>>>(h1, W2, root2, b2, s, out);

    k_aggregate2<<<(N_EDGES + 255) / 256, 256, 0, stream>>>(ei, et, cnt, s, out);
}

// Round 2
// 407.086 us; speedup vs baseline: 2.0412x; 2.0412x over previous
//
#include <hip/hip_runtime.h>

#define N_NODES 100000
#define N_EDGES 1600000
#define HIDDEN 64
#define SCAN_CHUNK 512
#define SCAN_NBLK 196  // ceil(100000/512)

// ---------------------------------------------------------------- K1: per-edge type + per-(dst,rel) histogram
__global__ void k_prep(const int* __restrict__ ei, const int* __restrict__ ntype,
                       int* __restrict__ ps, int* __restrict__ cnt) {
    int e = blockIdx.x * blockDim.x + threadIdx.x;
    if (e >= N_EDGES) return;
    int s = ei[e], d = ei[N_EDGES + e];
    int t = (ntype[s] == ntype[d]) ? 1 : 0;
    ps[e] = (s << 1) | t;
    atomicAdd(&cnt[d * 2 + t], 1);
}

// ---------------------------------------------------------------- K2a: per-block degree sums
__global__ void k_blocksum(const int* __restrict__ cnt, int* __restrict__ bsum) {
    __shared__ int sc[SCAN_CHUNK];
    int tid = threadIdx.x;
    int n = blockIdx.x * SCAN_CHUNK + tid;
    int deg = (n < N_NODES) ? (cnt[2 * n] + cnt[2 * n + 1]) : 0;
    sc[tid] = deg;
    __syncthreads();
    for (int off = SCAN_CHUNK / 2; off >= 1; off >>= 1) {
        if (tid < off) sc[tid] += sc[tid + off];
        __syncthreads();
    }
    if (tid == 0) bsum[blockIdx.x] = sc[0];
}

// ---------------------------------------------------------------- K2b: exclusive scan of block sums (1 block)
__global__ void k_bscan(const int* __restrict__ bsum, int* __restrict__ boff) {
    __shared__ int sc[256];
    int tid = threadIdx.x;
    int v = (tid < SCAN_NBLK) ? bsum[tid] : 0;
    sc[tid] = v;
    __syncthreads();
    for (int off = 1; off < 256; off <<= 1) {
        int a = sc[tid];
        int b = (tid >= off) ? sc[tid - off] : 0;
        __syncthreads();
        sc[tid] = a + b;
        __syncthreads();
    }
    if (tid < SCAN_NBLK) boff[tid] = sc[tid] - v;  // exclusive
}

// ---------------------------------------------------------------- K2c: per-node exclusive prefix -> row_ptr
__global__ void k_rowptr(const int* __restrict__ cnt, const int* __restrict__ boff,
                         int* __restrict__ row_ptr) {
    __shared__ int sc[SCAN_CHUNK];
    int tid = threadIdx.x;
    int n = blockIdx.x * SCAN_CHUNK + tid;
    int deg = (n < N_NODES) ? (cnt[2 * n] + cnt[2 * n + 1]) : 0;
    sc[tid] = deg;
    __syncthreads();
    for (int off = 1; off < SCAN_CHUNK; off <<= 1) {
        int a = sc[tid];
        int b = (tid >= off) ? sc[tid - off] : 0;
        __syncthreads();
        sc[tid] = a + b;
        __syncthreads();
    }
    int incl = sc[tid];
    if (n < N_NODES) row_ptr[n] = boff[blockIdx.x] + incl - deg;
    if (n == N_NODES - 1) row_ptr[N_NODES] = boff[blockIdx.x] + incl;  // == E
}

// ---------------------------------------------------------------- K3: scatter edges into CSR slots
__global__ void k_scatter(const int* __restrict__ ei, const int* __restrict__ ps,
                          const int* __restrict__ row_ptr, int* __restrict__ fill,
                          int* __restrict__ csr) {
    int e = blockIdx.x * blockDim.x + threadIdx.x;
    if (e >= N_EDGES) return;
    int d = ei[N_EDGES + e];
    int pos = row_ptr[d] + atomicAdd(&fill[d], 1);
    csr[pos] = ps[e];
}

// ---------------------------------------------------------------- K4: gather-aggregate layer 1 (wave per dst node)
__global__ void k_gather1(const int* __restrict__ csr, const int* __restrict__ row_ptr,
                          const int* __restrict__ cnt, const int* __restrict__ x,
                          const float* __restrict__ emb, float* __restrict__ agg) {
    int gid = blockIdx.x * blockDim.x + threadIdx.x;
    int n = gid >> 6;
    int lane = gid & 63;
    if (n >= N_NODES) return;
    int beg = row_ptr[n], end = row_ptr[n + 1];
    float a0 = 0.f, a1 = 0.f;
    int j = beg;
    for (; j + 4 <= end; j += 4) {
        int p0 = csr[j], p1 = csr[j + 1], p2 = csr[j + 2], p3 = csr[j + 3];
        int x0 = x[p0 >> 1], x1 = x[p1 >> 1], x2 = x[p2 >> 1], x3 = x[p3 >> 1];
        float v0 = emb[(long long)x0 * HIDDEN + lane];
        float v1 = emb[(long long)x1 * HIDDEN + lane];
        float v2 = emb[(long long)x2 * HIDDEN + lane];
        float v3 = emb[(long long)x3 * HIDDEN + lane];
        a0 += (p0 & 1) ? 0.f : v0;  a1 += (p0 & 1) ? v0 : 0.f;
        a0 += (p1 & 1) ? 0.f : v1;  a1 += (p1 & 1) ? v1 : 0.f;
        a0 += (p2 & 1) ? 0.f : v2;  a1 += (p2 & 1) ? v2 : 0.f;
        a0 += (p3 & 1) ? 0.f : v3;  a1 += (p3 & 1) ? v3 : 0.f;
    }
    for (; j < end; ++j) {
        int p = csr[j];
        float v = emb[(long long)x[p >> 1] * HIDDEN + lane];
        a0 += (p & 1) ? 0.f : v;  a1 += (p & 1) ? v : 0.f;
    }
    int c0 = cnt[2 * n], c1 = cnt[2 * n + 1];
    float n0 = 1.0f / (float)(c0 > 1 ? c0 : 1);
    float n1 = 1.0f / (float)(c1 > 1 ? c1 : 1);
    agg[(long long)n * 128 + lane] = a0 * n0;
    agg[(long long)n * 128 + 64 + lane] = a1 * n1;
}

// ---------------------------------------------------------------- K5: fused layer1 transform + relu + layer2 node scalars
// 256 threads = 4 waves; each wave handles 8 nodes; grid 3125 blocks (exactly 100000 nodes)
__global__ void k_layer1_fused(const int* __restrict__ x, const float* __restrict__ emb,
                               const float* __restrict__ agg,
                               const float* __restrict__ W1, const float* __restrict__ root1,
                               const float* __restrict__ b1,
                               const float* __restrict__ W2, const float* __restrict__ root2,
                               const float* __restrict__ b2,
                               float* __restrict__ s, float* __restrict__ out) {
    __shared__ float la[4][8][192];
    int w = threadIdx.x >> 6;
    int o = threadIdx.x & 63;
    int base = blockIdx.x * 32 + w * 8;

#pragma unroll
    for (int nb = 0; nb < 8; ++nb) {
        int node = base + nb;
        la[w][nb][o]       = agg[(long long)node * 128 + o];
        la[w][nb][64 + o]  = agg[(long long)node * 128 + 64 + o];
        la[w][nb][128 + o] = emb[(long long)x[node] * HIDDEN + o];
    }
    __syncthreads();

    float b1v = b1[o];
    float acc[8];
#pragma unroll
    for (int nb = 0; nb < 8; ++nb) acc[nb] = b1v;

#pragma unroll 4
    for (int h = 0; h < 64; ++h) {
        float w0 = W1[h * 64 + o];
        float w1 = W1[4096 + h * 64 + o];
        float wr = root1[h * 64 + o];
#pragma unroll
        for (int nb = 0; nb < 8; ++nb) {
            acc[nb] += la[w][nb][h] * w0;
            acc[nb] += la[w][nb][64 + h] * w1;
            acc[nb] += la[w][nb][128 + h] * wr;
        }
    }

    float w2a = W2[o], w2b = W2[64 + o], r2 = root2[o];
    float b2v = b2[0];
#pragma unroll
    for (int nb = 0; nb < 8; ++nb) {
        float h1v = acc[nb] > 0.f ? acc[nb] : 0.f;
        float p0 = h1v * w2a, p1 = h1v * w2b, p2 = h1v * r2;
        for (int off = 32; off >= 1; off >>= 1) {
            p0 += __shfl_down(p0, off);
            p1 += __shfl_down(p1, off);
            p2 += __shfl_down(p2, off);
        }
        if (o == 0) {
            int node = base + nb;
            s[node] = p0;
            s[N_NODES + node] = p1;
            out[node] = p2 + b2v;
        }
    }
}

// ---------------------------------------------------------------- K6: layer-2 edge aggregation (gather, no atomics)
__global__ void k_gather2(const int* __restrict__ csr, const int* __restrict__ row_ptr,
                          const int* __restrict__ cnt, const float* __restrict__ s,
                          float* __restrict__ out) {
    int gid = blockIdx.x * blockDim.x + threadIdx.x;
    int n = gid >> 6;
    int lane = gid & 63;
    if (n >= N_NODES) return;
    int beg = row_ptr[n], end = row_ptr[n + 1];
    int c0 = cnt[2 * n], c1 = cnt[2 * n + 1];
    float n0 = 1.0f / (float)(c0 > 1 ? c0 : 1);
    float n1 = 1.0f / (float)(c1 > 1 ? c1 : 1);
    float acc = 0.f;
    for (int j = beg + lane; j < end; j += 64) {
        int p = csr[j];
        int src = p >> 1;
        int t = p & 1;
        acc += s[t * N_NODES + src] * (t ? n1 : n0);
    }
    for (int off = 32; off >= 1; off >>= 1) acc += __shfl_down(acc, off);
    if (lane == 0) out[n] += acc;
}

extern "C" void kernel_launch(void* const* d_in, const int* in_sizes, int n_in,
                              void* d_out, int out_size, void* d_ws, size_t ws_size,
                              hipStream_t stream) {
    const int* x      = (const int*)d_in[0];
    const int* ei     = (const int*)d_in[1];
    const int* ntype  = (const int*)d_in[2];
    const float* emb  = (const float*)d_in[3];
    const float* W1   = (const float*)d_in[4];
    const float* root1= (const float*)d_in[5];
    const float* b1   = (const float*)d_in[6];
    const float* W2   = (const float*)d_in[7];
    const float* root2= (const float*)d_in[8];
    const float* b2   = (const float*)d_in[9];
    float* out = (float*)d_out;

    char* ws = (char*)d_ws;
    size_t off = 0;
    auto alloc = [&](size_t bytes) -> void* {
        void* p = ws + off;
        off = (off + bytes + 255) & ~(size_t)255;
        return p;
    };
    int* cnt     = (int*)alloc((size_t)N_NODES * 2 * sizeof(int));
    int* ps      = (int*)alloc((size_t)N_EDGES * sizeof(int));
    int* csr     = (int*)alloc((size_t)N_EDGES * sizeof(int));
    int* row_ptr = (int*)alloc((size_t)(N_NODES + 1) * sizeof(int));
    int* fill    = (int*)alloc((size_t)N_NODES * sizeof(int));
    int* bsum    = (int*)alloc((size_t)SCAN_NBLK * sizeof(int));
    int* boff    = (int*)alloc((size_t)SCAN_NBLK * sizeof(int));
    float* agg   = (float*)alloc((size_t)N_NODES * 2 * HIDDEN * sizeof(float));
    float* s     = (float*)alloc((size_t)N_NODES * 2 * sizeof(float));

    hipMemsetAsync(cnt, 0, (size_t)N_NODES * 2 * sizeof(int), stream);
    hipMemsetAsync(fill, 0, (size_t)N_NODES * sizeof(int), stream);

    k_prep<<<(N_EDGES + 255) / 256, 256, 0, stream>>>(ei, ntype, ps, cnt);
    k_blocksum<<<SCAN_NBLK, SCAN_CHUNK, 0, stream>>>(cnt, bsum);
    k_bscan<<<1, 256, 0, stream>>>(bsum, boff);
    k_rowptr<<<SCAN_NBLK, SCAN_CHUNK, 0, stream>>>(cnt, boff, row_ptr);
    k_scatter<<<(N_EDGES + 255) / 256, 256, 0, stream>>>(ei, ps, row_ptr, fill, csr);

    k_gather1<<<(N_NODES * 64) / 256, 256, 0, stream>>>(csr, row_ptr, cnt, x, emb, agg);
    k_layer1_fused<<<N_NODES / 32, 256, 0, stream>>>(x, emb, agg, W1, root1, b1,
                                                     W2, root2, b2, s, out);
    k_gather2<<<(N_NODES * 64) / 256, 256, 0, stream>>>(csr, row_ptr, cnt, s, out);
}